// Round 3
// baseline (936.944 us; speedup 1.0000x reference)
//
#include <hip/hip_runtime.h>

#define BB 128
#define TT 1024
#define VV 192
#define HALF 96
#define NTHREADS 384
#define NWAVES 6
#define LN2 0.69314718055994530942f

typedef float floatx2 __attribute__((ext_vector_type(2)));

__launch_bounds__(NTHREADS, 1)
__global__ void crf_kernel(const float* __restrict__ emissions,
                           const int* __restrict__ tags,
                           const int* __restrict__ mask,
                           const float* __restrict__ trans,
                           const float* __restrict__ start_trans,
                           const float* __restrict__ end_trans,
                           float* __restrict__ out)
{
    const int b = blockIdx.x;
    const int tid = threadIdx.x;
    const int j = tid >> 1;       // column 0..191 (lane pairs share j)
    const int g = tid & 1;        // i-half: 0 or 1
    const int lane = tid & 63;
    const int wid = tid >> 6;

    // double-buffered Q vector in fp8-e5m2 ("bf8"), stale-q0-normalized
    __shared__ __align__(16) unsigned char qb[2][VV];
    __shared__ float wred[NWAVES];
    __shared__ float wg[NWAVES];
    __shared__ int   wsl[NWAVES];
    __shared__ float sh_logden;

    const float* em_b = emissions + (size_t)b * TT * VV;
    const int* mask_b = mask + b * TT;

    // ---- exp(transitions) half-column in registers: e[i'] = exp(T[g*96+i', j]) ----
    float e[HALF];
    {
        const int i0 = g * HALF;
        #pragma unroll
        for (int i = 0; i < HALF; ++i)
            e[i] = __expf(trans[(i0 + i) * VV + j]);
    }

    // ---- init: Q0[j] = e5m2(exp(start[j] + em[0,j])) ----
    {
        float a0 = start_trans[j] + em_b[j];
        if (g == 0) {
            float q = fminf(__expf(a0), 28672.f);
            int pk = __builtin_amdgcn_cvt_pk_bf8_f32(q, q, 0, false);
            qb[0][j] = (unsigned char)(pk & 0xff);
        }
    }
    float carry2 = 0.f;   // accumulated log2 normalizers (uniform across threads)
    __syncthreads();

    // ---- emission/mask software pipeline (depth 2) ----
    float eexp_cur = __expf(em_b[1 * VV + j]);   // exp(emit at t=1)
    float em_n1 = em_b[2 * VV + j];              // raw emit at t=2
    int mk_cur = mask_b[1];
    int mk_n1 = mask_b[2];

    int cur = 0;
    for (int t = 1; t < TT; ++t) {
        // prefetch for t+2 (clamped)
        int tp = (t + 2 < TT) ? (t + 2) : (TT - 1);
        float em_n2 = em_b[(size_t)tp * VV + j];
        int mk_n2 = mask_b[tp];

        // q0 reference: broadcast-read dword 0, convert byte 0
        unsigned int w0 = *(const unsigned int*)(&qb[cur][0]);
        floatx2 q01 = __builtin_amdgcn_cvt_pk_f32_bf8((int)w0, false);
        float q0 = q01.x;
        unsigned char prevb = qb[cur][j];   // own byte (mask=0 passthrough)

        // dot: s = sum_{i in half g} Q[i] * e[i]; Q broadcast as fp8 b128 chunks
        const uint4* p4 = (const uint4*)(&qb[cur][g * HALF]);
        float s0 = 0.f, s1 = 0.f, s2 = 0.f, s3 = 0.f;
        #pragma unroll
        for (int c = 0; c < HALF / 16; ++c) {
            uint4 w = p4[c];
            const int base = 16 * c;
            {
                floatx2 lo = __builtin_amdgcn_cvt_pk_f32_bf8((int)w.x, false);
                floatx2 hi = __builtin_amdgcn_cvt_pk_f32_bf8((int)w.x, true);
                s0 = fmaf(lo.x, e[base + 0], s0);
                s1 = fmaf(lo.y, e[base + 1], s1);
                s2 = fmaf(hi.x, e[base + 2], s2);
                s3 = fmaf(hi.y, e[base + 3], s3);
            }
            {
                floatx2 lo = __builtin_amdgcn_cvt_pk_f32_bf8((int)w.y, false);
                floatx2 hi = __builtin_amdgcn_cvt_pk_f32_bf8((int)w.y, true);
                s0 = fmaf(lo.x, e[base + 4], s0);
                s1 = fmaf(lo.y, e[base + 5], s1);
                s2 = fmaf(hi.x, e[base + 6], s2);
                s3 = fmaf(hi.y, e[base + 7], s3);
            }
            {
                floatx2 lo = __builtin_amdgcn_cvt_pk_f32_bf8((int)w.z, false);
                floatx2 hi = __builtin_amdgcn_cvt_pk_f32_bf8((int)w.z, true);
                s0 = fmaf(lo.x, e[base + 8], s0);
                s1 = fmaf(lo.y, e[base + 9], s1);
                s2 = fmaf(hi.x, e[base + 10], s2);
                s3 = fmaf(hi.y, e[base + 11], s3);
            }
            {
                floatx2 lo = __builtin_amdgcn_cvt_pk_f32_bf8((int)w.w, false);
                floatx2 hi = __builtin_amdgcn_cvt_pk_f32_bf8((int)w.w, true);
                s0 = fmaf(lo.x, e[base + 12], s0);
                s1 = fmaf(lo.y, e[base + 13], s1);
                s2 = fmaf(hi.x, e[base + 14], s2);
                s3 = fmaf(hi.y, e[base + 15], s3);
            }
        }
        float part = (s0 + s1) + (s2 + s3);

        // combine the two i-halves: adjacent lanes hold the same j
        float qfull = part + __shfl_xor(part, 1);

        // stale-normalized update: Qnew = qfull * eexp / q0
        float r = __builtin_amdgcn_rcpf(q0);
        float qnew = qfull * eexp_cur * r;

        carry2 += mk_cur ? __log2f(q0) : 0.f;

        if (g == 0) {
            float qc = fminf(qnew, 28672.f);
            int pk = __builtin_amdgcn_cvt_pk_bf8_f32(qc, qc, 0, false);
            unsigned char nb = mk_cur ? (unsigned char)(pk & 0xff) : prevb;
            qb[cur ^ 1][j] = nb;
        }

        // advance pipeline
        eexp_cur = __expf(em_n1);
        em_n1 = em_n2;
        mk_cur = mk_n1;
        mk_n1 = mk_n2;

        __syncthreads();
        cur ^= 1;
    }

    // ---- final lse: logden = ln2*carry2 + log(sum_j Q[j]*exp(end[j])) ----
    float v = 0.f;
    if (g == 0) {
        floatx2 qv = __builtin_amdgcn_cvt_pk_f32_bf8((int)(unsigned int)qb[cur][j], false);
        v = qv.x * __expf(end_trans[j]);
    }
    #pragma unroll
    for (int off = 1; off < 64; off <<= 1)
        v += __shfl_xor(v, off);
    if (lane == 0) wred[wid] = v;
    __syncthreads();
    if (tid == 0) {
        float ssum = 0.f;
        for (int w = 0; w < NWAVES; ++w) ssum += wred[w];
        sh_logden = LN2 * carry2 + __logf(ssum + 1e-8f);
    }

    // ---- gold score + seq_len (strided over t) ----
    float gp = 0.f;
    int sl = 0;
    for (int t = tid; t < TT; t += NTHREADS) {
        sl += mask_b[t];
        if (t >= 1) {
            int tg  = tags[b * TT + t];
            int tgp = tags[b * TT + t - 1];
            float term = em_b[(size_t)t * VV + tg] + trans[tgp * VV + tg];
            gp += mask_b[t] ? term : 0.f;
        }
    }
    #pragma unroll
    for (int off = 1; off < 64; off <<= 1) {
        gp += __shfl_xor(gp, off);
        sl += __shfl_xor(sl, off);
    }
    if (lane == 0) { wg[wid] = gp; wsl[wid] = sl; }
    __syncthreads();
    if (tid == 0) {
        float gold = 0.f; int seqs = 0;
        for (int w = 0; w < NWAVES; ++w) { gold += wg[w]; seqs += wsl[w]; }
        int tg0 = tags[b * TT];
        gold += start_trans[tg0] + em_b[tg0];
        int last_idx = seqs - 1;
        int tgl = tags[b * TT + last_idx];
        gold += end_trans[tgl];
        float seqf = fmaxf((float)seqs, 1.0f);
        out[b] = (sh_logden - gold) / seqf;
    }
}

extern "C" void kernel_launch(void* const* d_in, const int* in_sizes, int n_in,
                              void* d_out, int out_size, void* d_ws, size_t ws_size,
                              hipStream_t stream) {
    const float* emissions   = (const float*)d_in[0];
    const int*   tags        = (const int*)d_in[1];
    const int*   mask        = (const int*)d_in[2];
    const float* trans       = (const float*)d_in[3];
    const float* start_trans = (const float*)d_in[4];
    const float* end_trans   = (const float*)d_in[5];
    float* out = (float*)d_out;

    crf_kernel<<<BB, NTHREADS, 0, stream>>>(emissions, tags, mask, trans,
                                            start_trans, end_trans, out);
}

// Round 4
// 609.092 us; speedup vs baseline: 1.5383x; 1.5383x over previous
//
#include <hip/hip_runtime.h>

#define BB 128
#define TT 1024
#define VV 192
#define NTHREADS 256
#define NWAVES 4
#define LN2 0.69314718055994530942f

typedef short short8 __attribute__((ext_vector_type(8)));
typedef float floatx4 __attribute__((ext_vector_type(4)));

__device__ __forceinline__ unsigned short f32_to_bf16(float f) {
    unsigned int u = __float_as_uint(f);
    u += 0x7fffu + ((u >> 16) & 1u);   // RNE
    return (unsigned short)(u >> 16);
}
__device__ __forceinline__ float bf16_to_f32(unsigned short h) {
    return __uint_as_float(((unsigned int)h) << 16);
}

__launch_bounds__(NTHREADS, 1)
__global__ void crf_kernel(const float* __restrict__ emissions,
                           const int* __restrict__ tags,
                           const int* __restrict__ mask,
                           const float* __restrict__ trans,
                           const float* __restrict__ start_trans,
                           const float* __restrict__ end_trans,
                           float* __restrict__ out)
{
    const int b = blockIdx.x;
    const int tid = threadIdx.x;
    const int lane = tid & 63;
    const int wid = tid >> 6;        // 0..3
    const int quad = lane >> 4;      // 0..3
    const int col = lane & 15;       // 0..15

    // Q state as bf16 (double-buffered), exp(emissions) staged as f32
    __shared__ __align__(16) unsigned short qbuf[2][VV];
    __shared__ __align__(16) float pexp[2][VV];
    __shared__ float wred[NWAVES];
    __shared__ float wg[NWAVES];
    __shared__ int   wsl[NWAVES];
    __shared__ float sh_logden;

    const float* em_b = emissions + (size_t)b * TT * VV;
    const int* mask_b = mask + b * TT;

    // ---- E fragments in registers: 6 K-tiles x 3 N-tiles, bf16 ----
    // B-operand layout (16x16x32): col n = lane&15, k = quad*8 + r
    short8 ef[18];
    #pragma unroll
    for (int kt = 0; kt < 6; ++kt) {
        #pragma unroll
        for (int h = 0; h < 3; ++h) {
            const int kb = kt * 32 + quad * 8;
            const int n = wid * 48 + h * 16 + col;
            short8 v;
            #pragma unroll
            for (int r = 0; r < 8; ++r) {
                float x = __expf(trans[(kb + r) * VV + n]);
                v[r] = (short)f32_to_bf16(x);
            }
            ef[kt * 3 + h] = v;
        }
    }

    // ---- init Q0, prestage exp(em[1]) ----
    if (tid < VV) {
        float a0 = start_trans[tid] + em_b[tid];
        qbuf[0][tid] = f32_to_bf16(__expf(a0));
        pexp[1][tid] = __expf(em_b[VV + tid]);
    }
    float em_n1 = (tid < VV) ? em_b[2 * VV + tid] : 0.f;   // raw em at t=2
    int mk_cur = mask_b[1];
    int mk_n1 = mask_b[2];
    float carry2 = 0.f;
    __syncthreads();

    int cur = 0;
    for (int t = 1; t < TT; ++t) {
        // prefetch t+2 (clamped)
        const int tp = (t + 2 < TT) ? (t + 2) : (TT - 1);
        const int mk_n2 = mask_b[tp];
        float em_n2 = (tid < VV) ? em_b[(size_t)tp * VV + tid] : 0.f;

        // A-fragments: A[m][k] = Q[k] for all m (broadcast rows)
        const unsigned short* qc = qbuf[cur];
        short8 av[6];
        #pragma unroll
        for (int kt = 0; kt < 6; ++kt)
            av[kt] = *(const short8*)(qc + kt * 32 + quad * 8);
        float q0 = bf16_to_f32(qc[0]);

        floatx4 acc[3];
        #pragma unroll
        for (int h = 0; h < 3; ++h) acc[h] = (floatx4){0.f, 0.f, 0.f, 0.f};
        #pragma unroll
        for (int kt = 0; kt < 6; ++kt) {
            #pragma unroll
            for (int h = 0; h < 3; ++h)
                acc[h] = __builtin_amdgcn_mfma_f32_16x16x32_bf16(
                             av[kt], ef[kt * 3 + h], acc[h], 0, 0, 0);
        }

        // stale-normalized update: Qnew[n] = C[n] * exp(em[t][n]) / q0
        const float r = __builtin_amdgcn_rcpf(q0);
        carry2 += mk_cur ? __log2f(q0) : 0.f;

        if (lane < 16) {
            if (mk_cur) {
                #pragma unroll
                for (int h = 0; h < 3; ++h) {
                    const int n = wid * 48 + h * 16 + lane;
                    float qn = acc[h][0] * pexp[t & 1][n] * r;
                    qbuf[cur ^ 1][n] = f32_to_bf16(qn);
                }
            } else {
                #pragma unroll
                for (int h = 0; h < 3; ++h) {
                    const int n = wid * 48 + h * 16 + lane;
                    qbuf[cur ^ 1][n] = qc[n];
                }
            }
        }

        // stage exp(em[t+1]) for next step
        if (tid < VV) pexp[(t + 1) & 1][tid] = __expf(em_n1);
        em_n1 = em_n2;
        mk_cur = mk_n1;
        mk_n1 = mk_n2;

        __syncthreads();
        cur ^= 1;
    }

    // ---- final lse: logden = ln2*carry2 + log(sum_j Q[j]*exp(end[j])) ----
    float v = 0.f;
    if (tid < VV) v = bf16_to_f32(qbuf[cur][tid]) * __expf(end_trans[tid]);
    #pragma unroll
    for (int off = 1; off < 64; off <<= 1)
        v += __shfl_xor(v, off);
    if (lane == 0) wred[wid] = v;
    __syncthreads();
    if (tid == 0) {
        float ssum = 0.f;
        for (int w = 0; w < NWAVES; ++w) ssum += wred[w];
        sh_logden = LN2 * carry2 + __logf(ssum + 1e-8f);
    }

    // ---- gold score + seq_len (strided over t) ----
    float gp = 0.f;
    int sl = 0;
    for (int t = tid; t < TT; t += NTHREADS) {
        sl += mask_b[t];
        if (t >= 1) {
            int tg  = tags[b * TT + t];
            int tgp = tags[b * TT + t - 1];
            float term = em_b[(size_t)t * VV + tg] + trans[tgp * VV + tg];
            gp += mask_b[t] ? term : 0.f;
        }
    }
    #pragma unroll
    for (int off = 1; off < 64; off <<= 1) {
        gp += __shfl_xor(gp, off);
        sl += __shfl_xor(sl, off);
    }
    if (lane == 0) { wg[wid] = gp; wsl[wid] = sl; }
    __syncthreads();
    if (tid == 0) {
        float gold = 0.f; int seqs = 0;
        for (int w = 0; w < NWAVES; ++w) { gold += wg[w]; seqs += wsl[w]; }
        int tg0 = tags[b * TT];
        gold += start_trans[tg0] + em_b[tg0];
        int last_idx = seqs - 1;
        int tgl = tags[b * TT + last_idx];
        gold += end_trans[tgl];
        float seqf = fmaxf((float)seqs, 1.0f);
        out[b] = (sh_logden - gold) / seqf;
    }
}

extern "C" void kernel_launch(void* const* d_in, const int* in_sizes, int n_in,
                              void* d_out, int out_size, void* d_ws, size_t ws_size,
                              hipStream_t stream) {
    const float* emissions   = (const float*)d_in[0];
    const int*   tags        = (const int*)d_in[1];
    const int*   mask        = (const int*)d_in[2];
    const float* trans       = (const float*)d_in[3];
    const float* start_trans = (const float*)d_in[4];
    const float* end_trans   = (const float*)d_in[5];
    float* out = (float*)d_out;

    crf_kernel<<<BB, NTHREADS, 0, stream>>>(emissions, tags, mask, trans,
                                            start_trans, end_trans, out);
}

// Round 5
// 574.713 us; speedup vs baseline: 1.6303x; 1.0598x over previous
//
#include <hip/hip_runtime.h>

#define BB 128
#define TT 1024
#define VV 192
#define NTHREADS 256
#define NWAVES 4
#define LN2 0.69314718055994530942f

typedef short short8 __attribute__((ext_vector_type(8)));
typedef float floatx4 __attribute__((ext_vector_type(4)));

__device__ __forceinline__ unsigned short f32_to_bf16(float f) {
    unsigned int u = __float_as_uint(f);
    u += 0x7fffu + ((u >> 16) & 1u);   // RNE
    return (unsigned short)(u >> 16);
}
__device__ __forceinline__ float bf16_to_f32(unsigned short h) {
    return __uint_as_float(((unsigned int)h) << 16);
}

// LDS-only barrier: wait LDS ops, sync waves — does NOT drain vmcnt, so
// outstanding global prefetch loads stay in flight across steps.
#define LBAR() __asm__ volatile("s_waitcnt lgkmcnt(0)\n\ts_barrier" ::: "memory")

__launch_bounds__(NTHREADS, 1)
__global__ void crf_kernel(const float* __restrict__ emissions,
                           const int* __restrict__ tags,
                           const int* __restrict__ mask,
                           const float* __restrict__ trans,
                           const float* __restrict__ start_trans,
                           const float* __restrict__ end_trans,
                           float* __restrict__ out)
{
    const int b = blockIdx.x;
    const int tid = threadIdx.x;
    const int lane = tid & 63;
    const int wid = tid >> 6;        // 0..3
    const int quad = lane >> 4;      // 0..3
    const int col = lane & 15;       // 0..15

    __shared__ __align__(16) unsigned short qbuf[2][VV];
    __shared__ __align__(16) float pexp[2][VV];
    __shared__ int smask[TT];
    __shared__ float wred[NWAVES];
    __shared__ float wg[NWAVES];
    __shared__ int   wsl[NWAVES];
    __shared__ float sh_logden;

    const float* em_b = emissions + (size_t)b * TT * VV;
    const int* mask_b = mask + b * TT;

    // ---- E fragments in registers: 6 K-tiles x 3 N-tiles, bf16 ----
    // B-operand layout (16x16x32): col n = lane&15, k = quad*8 + r
    short8 ef[18];
    #pragma unroll
    for (int kt = 0; kt < 6; ++kt) {
        #pragma unroll
        for (int h = 0; h < 3; ++h) {
            const int kb = kt * 32 + quad * 8;
            const int n = wid * 48 + h * 16 + col;
            short8 v;
            #pragma unroll
            for (int r = 0; r < 8; ++r) {
                float x = __expf(trans[(kb + r) * VV + n]);
                v[r] = (short)f32_to_bf16(x);
            }
            ef[kt * 3 + h] = v;
        }
    }

    // ---- preload mask into LDS (removes per-step global traffic) ----
    for (int t = tid; t < TT; t += NTHREADS) smask[t] = mask_b[t];

    // ---- preload emission rows [0,8) and [8,16) into registers ----
    float emA[8], emB[8];
    if (tid < VV) {
        #pragma unroll
        for (int r = 0; r < 8; ++r) emA[r] = em_b[(size_t)r * VV + tid];
        #pragma unroll
        for (int r = 0; r < 8; ++r) emB[r] = em_b[(size_t)(8 + r) * VV + tid];
    }

    // ---- init Q0 and pexp for t=1 ----
    if (tid < VV) {
        float a0 = start_trans[tid] + emA[0];
        qbuf[0][tid] = f32_to_bf16(__expf(a0));
        pexp[1][tid] = __expf(emA[1]);
    }
    float carry2 = 0.f;
    int cur = 0;
    __syncthreads();

    // one CRF step: consumes Q=qbuf[cur], pexp[t&1]; emnext = raw em[t+1][tid]
    auto dostep = [&](int t, float emnext) {
        const unsigned short* qc = qbuf[cur];
        short8 av[6];
        #pragma unroll
        for (int kt = 0; kt < 6; ++kt)
            av[kt] = *(const short8*)(qc + kt * 32 + quad * 8);
        float q0 = bf16_to_f32(qc[0]);
        int mk = smask[t];

        floatx4 acc[3];
        #pragma unroll
        for (int h = 0; h < 3; ++h) acc[h] = (floatx4){0.f, 0.f, 0.f, 0.f};
        #pragma unroll
        for (int kt = 0; kt < 6; ++kt) {
            #pragma unroll
            for (int h = 0; h < 3; ++h)
                acc[h] = __builtin_amdgcn_mfma_f32_16x16x32_bf16(
                             av[kt], ef[kt * 3 + h], acc[h], 0, 0, 0);
        }

        float r = __builtin_amdgcn_rcpf(q0);
        carry2 += mk ? __log2f(q0) : 0.f;

        const float* pe = pexp[t & 1];
        if (lane < 16) {
            if (mk) {
                #pragma unroll
                for (int h = 0; h < 3; ++h) {
                    const int n = wid * 48 + h * 16 + lane;
                    qbuf[cur ^ 1][n] = f32_to_bf16(acc[h][0] * pe[n] * r);
                }
            } else {
                #pragma unroll
                for (int h = 0; h < 3; ++h) {
                    const int n = wid * 48 + h * 16 + lane;
                    qbuf[cur ^ 1][n] = qc[n];
                }
            }
        }
        if (tid < VV) pexp[(t + 1) & 1][tid] = __expf(emnext);
        LBAR();
        cur ^= 1;
    };

    // ---- main loop: 16-step bodies; emA/emB refilled right after last use ----
    for (int t0 = 0; t0 < TT; t0 += 16) {
        if (t0 > 0) dostep(t0 + 0, emA[1]);
        dostep(t0 + 1, emA[2]);
        dostep(t0 + 2, emA[3]);
        dostep(t0 + 3, emA[4]);
        dostep(t0 + 4, emA[5]);
        dostep(t0 + 5, emA[6]);
        dostep(t0 + 6, emA[7]);
        // refill emA <- rows [t0+16, t0+24)  (first use: 8 steps away)
        if (tid < VV) {
            #pragma unroll
            for (int r = 0; r < 8; ++r) {
                int rr = t0 + 16 + r; rr = rr < TT ? rr : TT - 1;
                emA[r] = em_b[(size_t)rr * VV + tid];
            }
        }
        dostep(t0 + 7,  emB[0]);
        dostep(t0 + 8,  emB[1]);
        dostep(t0 + 9,  emB[2]);
        dostep(t0 + 10, emB[3]);
        dostep(t0 + 11, emB[4]);
        dostep(t0 + 12, emB[5]);
        dostep(t0 + 13, emB[6]);
        dostep(t0 + 14, emB[7]);
        // refill emB <- rows [t0+24, t0+32)  (first use: 8 steps away)
        if (tid < VV) {
            #pragma unroll
            for (int r = 0; r < 8; ++r) {
                int rr = t0 + 24 + r; rr = rr < TT ? rr : TT - 1;
                emB[r] = em_b[(size_t)rr * VV + tid];
            }
        }
        dostep(t0 + 15, emA[0]);
    }

    // ---- final lse: logden = ln2*carry2 + log(sum_j Q[j]*exp(end[j])) ----
    float v = 0.f;
    if (tid < VV) v = bf16_to_f32(qbuf[cur][tid]) * __expf(end_trans[tid]);
    #pragma unroll
    for (int off = 1; off < 64; off <<= 1)
        v += __shfl_xor(v, off);
    if (lane == 0) wred[wid] = v;
    __syncthreads();
    if (tid == 0) {
        float ssum = 0.f;
        for (int w = 0; w < NWAVES; ++w) ssum += wred[w];
        sh_logden = LN2 * carry2 + __logf(ssum + 1e-8f);
    }

    // ---- gold score + seq_len (strided over t) ----
    float gp = 0.f;
    int sl = 0;
    for (int t = tid; t < TT; t += NTHREADS) {
        sl += smask[t];
        if (t >= 1) {
            int tg  = tags[b * TT + t];
            int tgp = tags[b * TT + t - 1];
            float term = em_b[(size_t)t * VV + tg] + trans[tgp * VV + tg];
            gp += smask[t] ? term : 0.f;
        }
    }
    #pragma unroll
    for (int off = 1; off < 64; off <<= 1) {
        gp += __shfl_xor(gp, off);
        sl += __shfl_xor(sl, off);
    }
    if (lane == 0) { wg[wid] = gp; wsl[wid] = sl; }
    __syncthreads();
    if (tid == 0) {
        float gold = 0.f; int seqs = 0;
        for (int w = 0; w < NWAVES; ++w) { gold += wg[w]; seqs += wsl[w]; }
        int tg0 = tags[b * TT];
        gold += start_trans[tg0] + em_b[tg0];
        int last_idx = seqs - 1;
        int tgl = tags[b * TT + last_idx];
        gold += end_trans[tgl];
        float seqf = fmaxf((float)seqs, 1.0f);
        out[b] = (sh_logden - gold) / seqf;
    }
}

extern "C" void kernel_launch(void* const* d_in, const int* in_sizes, int n_in,
                              void* d_out, int out_size, void* d_ws, size_t ws_size,
                              hipStream_t stream) {
    const float* emissions   = (const float*)d_in[0];
    const int*   tags        = (const int*)d_in[1];
    const int*   mask        = (const int*)d_in[2];
    const float* trans       = (const float*)d_in[3];
    const float* start_trans = (const float*)d_in[4];
    const float* end_trans   = (const float*)d_in[5];
    float* out = (float*)d_out;

    crf_kernel<<<BB, NTHREADS, 0, stream>>>(emissions, tags, mask, trans,
                                            start_trans, end_trans, out);
}